// Round 3
// baseline (97.591 us; speedup 1.0000x reference)
//
#include <hip/hip_runtime.h>

typedef __attribute__((ext_vector_type(8))) __bf16 bf16x8;
typedef __attribute__((ext_vector_type(8))) unsigned short ushort8;
typedef __attribute__((ext_vector_type(4))) unsigned short ushort4v;
typedef __attribute__((ext_vector_type(4))) float f32x4;

namespace {
constexpr int kB = 8, kC = 128, kF = 256, kT = 128;

// ---- LDS map (ushort elements, 20480 total = 40 KB) ----
// [0, 16384)      : XT[t=128][p=128]  p = position-permuted channel axis (tau), XOR-swizzled.
//                   Aliased after phase C by UT[ri][e][s].
// [16384, 20480)  : K[mat=2][c=64][p=32]  p = position-permuted d axis (delta).
__device__ __forceinline__ int addrXT(int t, int p) { return t * 128 + (p ^ ((t & 7) << 3)); }
__device__ __forceinline__ int addrU(int ri, int e, int s) { return ri * 8192 + e * 128 + (s ^ ((e & 7) << 3)); }
__device__ __forceinline__ int addrK(int m, int c, int p) { return 16384 + m * 2048 + c * 32 + (p ^ ((c & 3) << 3)); }

__device__ __forceinline__ unsigned short b16(float f) {
    __bf16 h = (__bf16)f;
    return __builtin_bit_cast(unsigned short, h);
}

__device__ __forceinline__ bf16x8 ldfrag(const unsigned short* lds, int idx) {
    return __builtin_bit_cast(bf16x8, *(const ushort8*)(lds + idx));
}

__device__ __forceinline__ bf16x8 fneg(bf16x8 a) {
    ushort8 u = __builtin_bit_cast(ushort8, a);
    u ^= (unsigned short)0x8000;
    return __builtin_bit_cast(bf16x8, u);
}

// 8 consecutive fp32 from global -> bf16x8 fragment
__device__ __forceinline__ bf16x8 fragWg(const float* p) {
    f32x4 a = *(const f32x4*)p;
    f32x4 c = *(const f32x4*)(p + 4);
    bf16x8 r;
    r[0] = (__bf16)a[0]; r[1] = (__bf16)a[1]; r[2] = (__bf16)a[2]; r[3] = (__bf16)a[3];
    r[4] = (__bf16)c[0]; r[5] = (__bf16)c[1]; r[6] = (__bf16)c[2]; r[7] = (__bf16)c[3];
    return r;
}
} // namespace

__global__ __launch_bounds__(256, 4)
void chanattn_mfma2(const float* __restrict__ x,
                    const float* __restrict__ Wk, const float* __restrict__ bk,
                    const float* __restrict__ Wq, const float* __restrict__ bq,
                    const float* __restrict__ Wv, const float* __restrict__ bv,
                    float* __restrict__ out)
{
    __shared__ __align__(16) unsigned short lds[20480];

    const int f = blockIdx.x, b = blockIdx.y;
    const int tid = threadIdx.x;
    const int lane = tid & 63;
    const int w = tid >> 6;          // wave id 0..3
    const int lr = lane & 15;
    const int lg = lane >> 4;
    const size_t cstr = (size_t)kF * kT;
    const float* xb = x + ((size_t)b * kC * kF + f) * kT; // xb[c*cstr + t]

    // ============ Phase A: per-wave K (-> LDS, permuted d) + Q (-> registers) ============
    bf16x8 bqr, bqi;
    {
        bf16x8 xr_f[4], xi_f[4];
        #pragma unroll
        for (int ks = 0; ks < 4; ++ks) {
            xr_f[ks] = fragWg(xb + (size_t)(16 * w + lr) * cstr + ks * 32 + 8 * lg);
            xi_f[ks] = fragWg(xb + (size_t)(64 + 16 * w + lr) * cstr + ks * 32 + 8 * lg);
        }
        f32x4 qacc[2][2], kacc[2][2];   // [ri][dt]
        #pragma unroll
        for (int ri = 0; ri < 2; ++ri)
            #pragma unroll
            for (int dt = 0; dt < 2; ++dt) {
                qacc[ri][dt] = (f32x4){0.f, 0.f, 0.f, 0.f};
                kacc[ri][dt] = (f32x4){0.f, 0.f, 0.f, 0.f};
            }
        #pragma unroll
        for (int dt = 0; dt < 2; ++dt)
            #pragma unroll
            for (int ks = 0; ks < 4; ++ks) {
                bf16x8 wq = fragWg(Wq + (size_t)(16 * dt + lr) * kT + ks * 32 + 8 * lg);
                bf16x8 wk = fragWg(Wk + (size_t)(16 * dt + lr) * kT + ks * 32 + 8 * lg);
                qacc[0][dt] = __builtin_amdgcn_mfma_f32_16x16x32_bf16(wq, xr_f[ks], qacc[0][dt], 0, 0, 0);
                qacc[1][dt] = __builtin_amdgcn_mfma_f32_16x16x32_bf16(wq, xi_f[ks], qacc[1][dt], 0, 0, 0);
                kacc[0][dt] = __builtin_amdgcn_mfma_f32_16x16x32_bf16(xr_f[ks], wk, kacc[0][dt], 0, 0, 0);
                kacc[1][dt] = __builtin_amdgcn_mfma_f32_16x16x32_bf16(xi_f[ks], wk, kacc[1][dt], 0, 0, 0);
            }
        // K -> LDS: value for d=16*dt+lr stored at position p = 8*((lr>>2)&3) + 4*dt + (lr&3)
        const float bk0 = bk[lr], bk1 = bk[16 + lr];
        #pragma unroll
        for (int dt = 0; dt < 2; ++dt) {
            const int pcol = 8 * ((lr >> 2) & 3) + 4 * dt + (lr & 3);
            const float bb = dt ? bk1 : bk0;
            #pragma unroll
            for (int r = 0; r < 4; ++r) {
                const int c = 16 * w + 4 * lg + r;
                lds[addrK(0, c, pcol)] = b16(kacc[0][dt][r] + bb);
                lds[addrK(1, c, pcol)] = b16(kacc[1][dt][r] + bb);
            }
        }
        // Q -> B-frags in-register: element j <- slot(dt=j>>2, r=j&3)  (delta permutation)
        #pragma unroll
        for (int j = 0; j < 8; ++j) {
            const int dt = j >> 2, r = j & 3;
            const float bb = bq[16 * dt + 4 * lg + r];
            bqr[j] = (__bf16)(qacc[0][dt][r] + bb);
            bqi[j] = (__bf16)(qacc[1][dt][r] + bb);
        }
    }

    // ============ Phase 0: x -> XT[t][p] (bf16, tau-permuted c axis, swizzled) ============
    {
        const int c0 = 4 * (tid & 31);           // channel quad 0..124
        const int t0 = 4 * (tid >> 5);           // 0..28
        // position quad for c0 (tau^-1, preserves low 2 bits):
        const int h  = c0 >> 6;
        const int cc = c0 & 63;
        const int p0 = 64 * h + 32 * (cc >> 5) + 8 * ((cc >> 2) & 3) + 4 * ((cc >> 4) & 1);
        #pragma unroll
        for (int tp = 0; tp < 4; ++tp) {
            const int t = t0 + 32 * tp;
            f32x4 v[4];
            #pragma unroll
            for (int j = 0; j < 4; ++j)
                v[j] = *(const f32x4*)(xb + (size_t)(c0 + j) * cstr + t);
            #pragma unroll
            for (int i = 0; i < 4; ++i) {
                ushort4v pk;
                pk[0] = b16(v[0][i]); pk[1] = b16(v[1][i]);
                pk[2] = b16(v[2][i]); pk[3] = b16(v[3][i]);
                *(ushort4v*)&lds[addrXT(t + i, p0)] = pk;
            }
        }
    }
    __syncthreads();   // barrier 1: XT + K ready

    // ============ Phase B: P = K^T Q (complex), softmax over c; W stays in registers ======
    f32x4 pr[4], pi[4];
    float inv_r, inv_i;
    {
        const f32x4 zero = {0.f, 0.f, 0.f, 0.f};
        #pragma unroll
        for (int ct = 0; ct < 4; ++ct) {
            bf16x8 akr = ldfrag(lds, addrK(0, ct * 16 + lr, 8 * lg));
            bf16x8 aki = ldfrag(lds, addrK(1, ct * 16 + lr, 8 * lg));
            pr[ct] = __builtin_amdgcn_mfma_f32_16x16x32_bf16(akr, bqr, zero, 0, 0, 0);
            pr[ct] = __builtin_amdgcn_mfma_f32_16x16x32_bf16(fneg(aki), bqi, pr[ct], 0, 0, 0);
            pi[ct] = __builtin_amdgcn_mfma_f32_16x16x32_bf16(akr, bqi, zero, 0, 0, 0);
            pi[ct] = __builtin_amdgcn_mfma_f32_16x16x32_bf16(aki, bqr, pi[ct], 0, 0, 0);
        }
        float mr = -1e30f, mi = -1e30f;
        #pragma unroll
        for (int ct = 0; ct < 4; ++ct)
            #pragma unroll
            for (int r = 0; r < 4; ++r) { mr = fmaxf(mr, pr[ct][r]); mi = fmaxf(mi, pi[ct][r]); }
        mr = fmaxf(mr, __shfl_xor(mr, 16)); mr = fmaxf(mr, __shfl_xor(mr, 32));
        mi = fmaxf(mi, __shfl_xor(mi, 16)); mi = fmaxf(mi, __shfl_xor(mi, 32));
        float sr = 0.f, si = 0.f;
        #pragma unroll
        for (int ct = 0; ct < 4; ++ct)
            #pragma unroll
            for (int r = 0; r < 4; ++r) {
                float er = __expf(pr[ct][r] - mr); pr[ct][r] = er; sr += er;
                float ei = __expf(pi[ct][r] - mi); pi[ct][r] = ei; si += ei;
            }
        sr += __shfl_xor(sr, 16); sr += __shfl_xor(sr, 32);
        si += __shfl_xor(si, 16); si += __shfl_xor(si, 32);
        inv_r = 1.f / sr; inv_i = 1.f / si;
    }

    // W A-frags in-register: element (ks, j) <- slot(ct = 2*ks + (j>>2), r = j&3)  (tau)
    bf16x8 awr[2], awi[2], awin[2];
    #pragma unroll
    for (int ks = 0; ks < 2; ++ks) {
        #pragma unroll
        for (int j = 0; j < 8; ++j) {
            const int ct = 2 * ks + (j >> 2), r = j & 3;
            awr[ks][j] = (__bf16)(pr[ct][r] * inv_r);
            awi[ks][j] = (__bf16)(pi[ct][r] * inv_i);
        }
        awin[ks] = fneg(awi[ks]);
    }

    // ============ Phase C: U[e][t] = sum_c W[c][e] X[c][t] (complex), in registers ========
    f32x4 uacc_r[8], uacc_i[8];
    #pragma unroll
    for (int nt = 0; nt < 8; ++nt) {
        f32x4 ur = {0.f, 0.f, 0.f, 0.f}, ui = {0.f, 0.f, 0.f, 0.f};
        #pragma unroll
        for (int ks = 0; ks < 2; ++ks) {
            bf16x8 bxr = ldfrag(lds, addrXT(nt * 16 + lr, ks * 32 + 8 * lg));
            bf16x8 bxi = ldfrag(lds, addrXT(nt * 16 + lr, 64 + ks * 32 + 8 * lg));
            ur = __builtin_amdgcn_mfma_f32_16x16x32_bf16(awr[ks], bxr, ur, 0, 0, 0);
            ur = __builtin_amdgcn_mfma_f32_16x16x32_bf16(awin[ks], bxi, ur, 0, 0, 0);
            ui = __builtin_amdgcn_mfma_f32_16x16x32_bf16(awi[ks], bxr, ui, 0, 0, 0);
            ui = __builtin_amdgcn_mfma_f32_16x16x32_bf16(awr[ks], bxi, ui, 0, 0, 0);
        }
        uacc_r[nt] = ur; uacc_i[nt] = ui;
    }
    __syncthreads();   // barrier 2: all waves done reading XT
    #pragma unroll
    for (int nt = 0; nt < 8; ++nt)
        #pragma unroll
        for (int r = 0; r < 4; ++r) {
            const int e = 16 * w + 4 * lg + r;
            lds[addrU(0, e, nt * 16 + lr)] = b16(uacc_r[nt][r]);
            lds[addrU(1, e, nt * 16 + lr)] = b16(uacc_i[nt][r]);
        }
    __syncthreads();   // barrier 3: UT ready

    // ============ Phase D: O[t'][e] = Wv * U (+2bv on imag), store fp32 ============
    {
        #pragma unroll
        for (int mi_ = 0; mi_ < 2; ++mi_) {
            const int mt = 2 * w + mi_;      // t'-tile 0..7
            bf16x8 av[4];
            #pragma unroll
            for (int ks = 0; ks < 4; ++ks)
                av[ks] = fragWg(Wv + (size_t)(mt * 16 + lr) * kT + ks * 32 + 8 * lg);
            float bvv[4];
            #pragma unroll
            for (int r = 0; r < 4; ++r) bvv[r] = 2.f * bv[mt * 16 + 4 * lg + r];

            #pragma unroll
            for (int et = 0; et < 4; ++et) {
                f32x4 aor = {0.f, 0.f, 0.f, 0.f}, aoi = {0.f, 0.f, 0.f, 0.f};
                #pragma unroll
                for (int ks = 0; ks < 4; ++ks) {
                    bf16x8 bur = ldfrag(lds, addrU(0, et * 16 + lr, ks * 32 + 8 * lg));
                    bf16x8 bui = ldfrag(lds, addrU(1, et * 16 + lr, ks * 32 + 8 * lg));
                    aor = __builtin_amdgcn_mfma_f32_16x16x32_bf16(av[ks], bur, aor, 0, 0, 0);
                    aoi = __builtin_amdgcn_mfma_f32_16x16x32_bf16(av[ks], bui, aoi, 0, 0, 0);
                }
                const int e = et * 16 + lr;
                const int tp0 = mt * 16 + 4 * lg;
                f32x4 vi;
                #pragma unroll
                for (int r = 0; r < 4; ++r) vi[r] = aoi[r] + bvv[r];
                *(f32x4*)(out + (((size_t)b * kC + e) * kF + f) * kT + tp0)      = aor;
                *(f32x4*)(out + (((size_t)b * kC + 64 + e) * kF + f) * kT + tp0) = vi;
            }
        }
    }
}

extern "C" void kernel_launch(void* const* d_in, const int* in_sizes, int n_in,
                              void* d_out, int out_size, void* d_ws, size_t ws_size,
                              hipStream_t stream) {
    const float* x  = (const float*)d_in[0];
    const float* Wk = (const float*)d_in[1];
    const float* bk = (const float*)d_in[2];
    const float* Wq = (const float*)d_in[3];
    const float* bq = (const float*)d_in[4];
    const float* Wv = (const float*)d_in[5];
    const float* bv = (const float*)d_in[6];
    float* out = (float*)d_out;

    dim3 grid(kF, kB);   // one block per (b, f)
    dim3 block(256);
    chanattn_mfma2<<<grid, block, 0, stream>>>(x, Wk, bk, Wq, bq, Wv, bv, out);
}